// Round 4
// baseline (924.899 us; speedup 1.0000x reference)
//
#include <hip/hip_runtime.h>

// ============================================================================
// GSTVQA forward, MI355X.  Round 4: revert to the PROVEN round-1 GEMM
// geometry (the 2.97-absmax kernel), upgrade precision inside it:
//  - all GEMM operands staged as RAW FP32 in LDS, split in-register to
//    3-way truncated bf16 (hi+mid+lo), 6 MFMAs/product => rel err ~1.8e-7
//  - single f32 accumulator (noise < f32 reference's own accum noise)
//  - intermediates h1/feat stored plain fp32 (no split planes anywhere)
//  - GRU hidden dots + attention convs + pyramid S/A + score in FP64
//    (removes the ~2.9 f32-tail floor identified from rounds 0/1)
// Folds: W1' = W1*diag(1/sig) (f64), b1' folds mu; Wc = W_ih@W_ann (f64).
// ============================================================================

typedef unsigned short u16t;
typedef unsigned int   u32t;
typedef float  f32x4 __attribute__((ext_vector_type(4)));
typedef u32t   u32x4 __attribute__((ext_vector_type(4)));
typedef __bf16 bf16x8 __attribute__((ext_vector_type(8)));

__device__ __forceinline__ f32x4 mfma_b(u32x4 a, u32x4 b, f32x4 c){
  return __builtin_amdgcn_mfma_f32_16x16x32_bf16(
      __builtin_bit_cast(bf16x8, a), __builtin_bit_cast(bf16x8, b), c, 0, 0, 0);
}

#define GLDS16(SRC, DST)                                                    \
  __builtin_amdgcn_global_load_lds(                                         \
      (const __attribute__((address_space(1))) void*)(SRC),                 \
      (__attribute__((address_space(3))) void*)(DST), 16, 0, 0)

// residual after truncating to bf16: r = x - trunc16(x)
__device__ __forceinline__ u32t resid(u32t u){
  float d = __uint_as_float(u) - __uint_as_float(u & 0xFFFF0000u);
  return __float_as_uint(d);
}

// 8 fp32 (two 16B units, k-order) -> 3 bf16x8 planes (hi/mid/lo, truncated).
// x = H + M + L + eps, |eps| <= 2^-24 |x|.  Perm pattern proven in round 1.
__device__ __forceinline__ void split8_3(u32x4 a, u32x4 b,
                                         u32x4& H, u32x4& M, u32x4& L){
  u32t r1[8], r2[8];
#pragma unroll
  for (int j = 0; j < 4; j++){ r1[j] = resid(a[j]); r1[4 + j] = resid(b[j]); }
#pragma unroll
  for (int j = 0; j < 8; j++){ r2[j] = resid(r1[j]); }
  H[0] = __builtin_amdgcn_perm(a[1], a[0], 0x07060302u);
  H[1] = __builtin_amdgcn_perm(a[3], a[2], 0x07060302u);
  H[2] = __builtin_amdgcn_perm(b[1], b[0], 0x07060302u);
  H[3] = __builtin_amdgcn_perm(b[3], b[2], 0x07060302u);
  M[0] = __builtin_amdgcn_perm(r1[1], r1[0], 0x07060302u);
  M[1] = __builtin_amdgcn_perm(r1[3], r1[2], 0x07060302u);
  M[2] = __builtin_amdgcn_perm(r1[5], r1[4], 0x07060302u);
  M[3] = __builtin_amdgcn_perm(r1[7], r1[6], 0x07060302u);
  L[0] = __builtin_amdgcn_perm(r2[1], r2[0], 0x07060302u);
  L[1] = __builtin_amdgcn_perm(r2[3], r2[2], 0x07060302u);
  L[2] = __builtin_amdgcn_perm(r2[5], r2[4], 0x07060302u);
  L[3] = __builtin_amdgcn_perm(r2[7], r2[6], 0x07060302u);
}

// 6-term emulated-fp32 product into one accumulator (small terms first)
__device__ __forceinline__ void mfma6(const u32x4& AH, const u32x4& AM, const u32x4& AL,
                                      const u32x4& BH, const u32x4& BM, const u32x4& BL,
                                      f32x4& acc){
  acc = mfma_b(AL, BH, acc);
  acc = mfma_b(AM, BM, acc);
  acc = mfma_b(AH, BL, acc);
  acc = mfma_b(AM, BH, acc);
  acc = mfma_b(AH, BM, acc);
  acc = mfma_b(AH, BH, acc);
}

// ---------------------------------------------------------------- prep
__global__ __launch_bounds__(256) void prep_params_kernel(
    const float* __restrict__ mv, const float* __restrict__ sv,
    const float* __restrict__ mm, const float* __restrict__ sm,
    double* __restrict__ mu, double* __restrict__ rinv){
  int f = blockIdx.x * 256 + threadIdx.x;
  if (f < 2944){
    if (f < 1472){ mu[f] = (double)mv[f]; rinv[f] = 1.0 / (double)sv[f]; }
    else         { mu[f] = (double)mm[f - 1472]; rinv[f] = 1.0 / (double)sm[f - 1472]; }
  }
}

// W1' = W1 * diag(1/sig) (f64 fold) -> fp32
__global__ __launch_bounds__(256) void fold_w1_kernel(
    const float* __restrict__ w, const double* __restrict__ rinv,
    float* __restrict__ w1p){
  int id = blockIdx.x * 256 + threadIdx.x;
  if (id < 320 * 2944)
    w1p[id] = (float)((double)w[id] * rinv[id % 2944]);
}

// b1'[n] = b1[n] - sum_k W1[n,k]*mu[k]/sig[k]   (f64)
__global__ __launch_bounds__(64) void b1p_kernel(
    const float* __restrict__ w1, const float* __restrict__ b1,
    const double* __restrict__ mu, const double* __restrict__ rinv,
    float* __restrict__ b1p){
  int n = blockIdx.x, lane = threadIdx.x;
  double s = 0.0;
  for (int k = lane; k < 2944; k += 64)
    s += (double)w1[n * 2944 + k] * rinv[k] * mu[k];
#pragma unroll
  for (int o = 32; o > 0; o >>= 1) s += __shfl_xor(s, o);
  if (lane == 0) b1p[n] = (float)((double)b1[n] - s);
}

// Wc = gru_w_ih @ ann_w (f64) -> fp32; bc = gru_w_ih @ ann_b + gru_b_ih
__global__ __launch_bounds__(256) void make_wc_kernel(
    const float* __restrict__ wih, const float* __restrict__ annw,
    const float* __restrict__ annb, const float* __restrict__ bih,
    float* __restrict__ wc, float* __restrict__ bc){
  int id = blockIdx.x * 256 + threadIdx.x;
  if (id < 96 * 1472){
    int g = id / 1472, k = id - g * 1472;
    double s = 0.0;
    for (int r = 0; r < 256; r++)
      s += (double)wih[g * 256 + r] * (double)annw[r * 1472 + k];
    wc[id] = (float)s;
  } else if (id < 96 * 1472 + 96){
    int g = id - 96 * 1472;
    double s = (double)bih[g];
    for (int r = 0; r < 256; r++)
      s += (double)wih[g * 256 + r] * (double)annb[r];
    bc[g] = (float)s;
  }
}

// ---------------------------------------------------------------- G1
// h1 = relu(x @ W1'^T + b1'). BM=80, BN=320 (full), BK=32, 4 waves 1x4,
// wave tile 80x80 (fm=5, fn=5). A,B fp32 in LDS (128B rows, 8-slot XOR),
// 3-way split at fragment read.  [geometry = proven round-1 kernel]
__global__ __launch_bounds__(256) void gemm1_kernel(
    const float* __restrict__ x, const float* __restrict__ w1p,
    const float* __restrict__ b1p, float* __restrict__ h1){
  __shared__ float lA[80 * 32];    // 10 KB
  __shared__ float lB[320 * 32];   // 40 KB
  const int tid = threadIdx.x, wave = tid >> 6, lane = tid & 63;
  const int m0 = blockIdx.x * 80;
  const int l8 = lane >> 3, l7 = lane & 7;
  f32x4 acc[5][5] = {};
  for (int k0 = 0; k0 < 2944; k0 += 32){
    __syncthreads();
    for (int i = wave; i < 10; i += 4){
      int row = i * 8 + l8;
      GLDS16(x + (size_t)(m0 + row) * 2944 + k0 + ((l7 ^ (row & 7)) << 2), lA + (i << 8));
    }
    for (int i = wave; i < 40; i += 4){
      int row = i * 8 + l8;
      GLDS16(w1p + (size_t)row * 2944 + k0 + ((l7 ^ (row & 7)) << 2), lB + (i << 8));
    }
    __syncthreads();
    const int g = lane >> 4, r15 = lane & 15;
    u32x4 AH[5], AM[5], AL[5];
#pragma unroll
    for (int fm = 0; fm < 5; fm++){
      int row = fm * 16 + r15;
      const char* base = (const char*)lA + (row << 7);
      u32x4 a0 = *(const u32x4*)(base + ((((g << 1) + 0) ^ (row & 7)) << 4));
      u32x4 a1 = *(const u32x4*)(base + ((((g << 1) + 1) ^ (row & 7)) << 4));
      split8_3(a0, a1, AH[fm], AM[fm], AL[fm]);
    }
#pragma unroll
    for (int fn = 0; fn < 5; fn++){
      int row = wave * 80 + fn * 16 + r15;
      const char* base = (const char*)lB + (row << 7);
      u32x4 b0 = *(const u32x4*)(base + ((((g << 1) + 0) ^ (row & 7)) << 4));
      u32x4 b1v = *(const u32x4*)(base + ((((g << 1) + 1) ^ (row & 7)) << 4));
      u32x4 BH, BM, BL; split8_3(b0, b1v, BH, BM, BL);
#pragma unroll
      for (int fm = 0; fm < 5; fm++)
        mfma6(AH[fm], AM[fm], AL[fm], BH, BM, BL, acc[fm][fn]);
    }
  }
#pragma unroll
  for (int fn = 0; fn < 5; fn++){
    int col = wave * 80 + fn * 16 + (lane & 15);
    float bias = b1p[col];
#pragma unroll
    for (int fm = 0; fm < 5; fm++){
      int mb = m0 + fm * 16 + ((lane >> 4) << 2);
#pragma unroll
      for (int r = 0; r < 4; r++)
        h1[(size_t)(mb + r) * 320 + col] = fmaxf(acc[fm][fn][r] + bias, 0.f);
    }
  }
}

// ---------------------------------------------------------------- G2
// z = h1 @ W2^T (paired cols f, f+1472); feat = sig(z)-gated mix of
// normalized x.  BM=128, 64 f-values (128 B-rows), BK=32, waves 2x2
// (fm=4, fn=4).  B-row r -> w2row = ((r>>4)&1)*1472 + f0 + ((r>>5)<<4)+(r&15).
__global__ __launch_bounds__(256) void gemm2_kernel(
    const float* __restrict__ h1, const float* __restrict__ w2,
    const float* __restrict__ b2, const float* __restrict__ x,
    const double* __restrict__ mu, const double* __restrict__ rinv,
    float* __restrict__ feat){
  __shared__ float lA[128 * 32];   // 16 KB
  __shared__ float lB[128 * 32];   // 16 KB
  const int tid = threadIdx.x, wave = tid >> 6, lane = tid & 63;
  const int wm = wave >> 1, wn = wave & 1;
  const int f0 = blockIdx.x * 64, m0 = blockIdx.y * 128;
  const int l8 = lane >> 3, l7 = lane & 7;
  f32x4 acc[4][4] = {};
  for (int k0 = 0; k0 < 320; k0 += 32){
    __syncthreads();
    for (int i = wave; i < 16; i += 4){
      int row = i * 8 + l8;
      GLDS16(h1 + (size_t)(m0 + row) * 320 + k0 + ((l7 ^ (row & 7)) << 2), lA + (i << 8));
    }
    for (int i = wave; i < 16; i += 4){
      int row = i * 8 + l8;
      int w2row = (((row >> 4) & 1) * 1472) + f0 + ((row >> 5) << 4) + (row & 15);
      GLDS16(w2 + (size_t)w2row * 320 + k0 + ((l7 ^ (row & 7)) << 2), lB + (i << 8));
    }
    __syncthreads();
    const int g = lane >> 4, r15 = lane & 15;
    u32x4 AH[4], AM[4], AL[4];
#pragma unroll
    for (int fm = 0; fm < 4; fm++){
      int row = wm * 64 + fm * 16 + r15;
      const char* base = (const char*)lA + (row << 7);
      u32x4 a0 = *(const u32x4*)(base + ((((g << 1) + 0) ^ (row & 7)) << 4));
      u32x4 a1 = *(const u32x4*)(base + ((((g << 1) + 1) ^ (row & 7)) << 4));
      split8_3(a0, a1, AH[fm], AM[fm], AL[fm]);
    }
#pragma unroll
    for (int fn = 0; fn < 4; fn++){
      int row = wn * 64 + fn * 16 + r15;
      const char* base = (const char*)lB + (row << 7);
      u32x4 b0 = *(const u32x4*)(base + ((((g << 1) + 0) ^ (row & 7)) << 4));
      u32x4 b1v = *(const u32x4*)(base + ((((g << 1) + 1) ^ (row & 7)) << 4));
      u32x4 BH, BM, BL; split8_3(b0, b1v, BH, BM, BL);
#pragma unroll
      for (int fm = 0; fm < 4; fm++)
        mfma6(AH[fm], AM[fm], AL[fm], BH, BM, BL, acc[fm][fn]);
    }
  }
#pragma unroll
  for (int cg = 0; cg < 2; cg++){
    int f = f0 + wn * 32 + cg * 16 + (lane & 15);
    float blo = b2[f], bhi = b2[1472 + f];
    double muv = mu[f], riv = rinv[f];
    double mum = mu[1472 + f], rim = rinv[1472 + f];
#pragma unroll
    for (int fm = 0; fm < 4; fm++){
      int mb = m0 + wm * 64 + fm * 16 + ((lane >> 4) << 2);
#pragma unroll
      for (int r = 0; r < 4; r++){
        int m = mb + r;
        float zl = acc[fm][2 * cg][r] + blo;
        float zh = acc[fm][2 * cg + 1][r] + bhi;
        float wl = 1.f / (1.f + expf(-zl));
        float wh = 1.f / (1.f + expf(-zh));
        float xv = (float)(((double)x[(size_t)m * 2944 + f] - muv) * riv);
        float xm = (float)(((double)x[(size_t)m * 2944 + 1472 + f] - mum) * rim);
        feat[(size_t)m * 1472 + f] = wl * xv + wh * xm;
      }
    }
  }
}

// ---------------------------------------------------------------- G3
// xg = feat @ Wc^T + bc. BM=64, BN=96, BK=64, waves 2x2 (32x48, fm=2 fn=3).
// fp32 LDS tiles with 256B rows (16-slot XOR).
__global__ __launch_bounds__(256) void gemm3_kernel(
    const float* __restrict__ feat, const float* __restrict__ wc,
    const float* __restrict__ bc, float* __restrict__ xg){
  __shared__ float lA[64 * 64];   // 16 KB
  __shared__ float lB[96 * 64];   // 24 KB
  const int tid = threadIdx.x, wave = tid >> 6, lane = tid & 63;
  const int wm = wave >> 1, wn = wave & 1;
  const int m0 = blockIdx.x * 64;
  const int l4 = lane >> 4, l15 = lane & 15;
  f32x4 acc[2][3] = {};
  for (int k0 = 0; k0 < 1472; k0 += 64){
    __syncthreads();
    for (int i = wave; i < 16; i += 4){
      int row = i * 4 + l4;
      GLDS16(feat + (size_t)(m0 + row) * 1472 + k0 + ((l15 ^ (row & 15)) << 2), lA + (i << 8));
    }
    for (int i = wave; i < 24; i += 4){
      int row = i * 4 + l4;
      GLDS16(wc + (size_t)row * 1472 + k0 + ((l15 ^ (row & 15)) << 2), lB + (i << 8));
    }
    __syncthreads();
    const int g = lane >> 4, r15 = lane & 15;
#pragma unroll
    for (int ks = 0; ks < 2; ks++){
      u32x4 AH[2], AM[2], AL[2];
#pragma unroll
      for (int fm = 0; fm < 2; fm++){
        int row = wm * 32 + fm * 16 + r15;
        const char* base = (const char*)lA + (row << 8);
        u32x4 a0 = *(const u32x4*)(base + (((ks * 8 + 2 * g + 0) ^ (row & 15)) << 4));
        u32x4 a1 = *(const u32x4*)(base + (((ks * 8 + 2 * g + 1) ^ (row & 15)) << 4));
        split8_3(a0, a1, AH[fm], AM[fm], AL[fm]);
      }
#pragma unroll
      for (int fn = 0; fn < 3; fn++){
        int row = wn * 48 + fn * 16 + r15;
        const char* base = (const char*)lB + (row << 8);
        u32x4 b0 = *(const u32x4*)(base + (((ks * 8 + 2 * g + 0) ^ (row & 15)) << 4));
        u32x4 b1v = *(const u32x4*)(base + (((ks * 8 + 2 * g + 1) ^ (row & 15)) << 4));
        u32x4 BH, BM, BL; split8_3(b0, b1v, BH, BM, BL);
#pragma unroll
        for (int fm = 0; fm < 2; fm++)
          mfma6(AH[fm], AM[fm], AL[fm], BH, BM, BL, acc[fm][fn]);
      }
    }
  }
#pragma unroll
  for (int fn = 0; fn < 3; fn++){
    int col = wn * 48 + fn * 16 + (lane & 15);
    float bias = bc[col];
#pragma unroll
    for (int fm = 0; fm < 2; fm++){
      int mb = m0 + wm * 32 + fm * 16 + ((lane >> 4) << 2);
#pragma unroll
      for (int r = 0; r < 4; r++)
        xg[(size_t)(mb + r) * 96 + col] = acc[fm][fn][r] + bias;
    }
  }
}

// ---------------------------------------------------------------- GRU
// One block per batch. tid<96: hg = h@Whh^T+bhh in f64; tid<32: gates.
__global__ __launch_bounds__(128) void gru_kernel(
    const float* __restrict__ xg, const float* __restrict__ whh,
    const float* __restrict__ bhh, float* __restrict__ outs){
  const int b = blockIdx.x, tid = threadIdx.x;
  __shared__ float hs[32];
  __shared__ double hg[96];
  double wr[32];
  double bias = 0.0;
  if (tid < 96){
#pragma unroll
    for (int j = 0; j < 32; j++) wr[j] = (double)whh[tid * 32 + j];
    bias = (double)bhh[tid];
  }
  if (tid < 32) hs[tid] = 0.f;
  __syncthreads();
  const float* xb = xg + (size_t)b * 300 * 96;
  float* ob = outs + (size_t)b * 300 * 32;
  for (int t = 0; t < 300; t++){
    if (tid < 96){
      double s0 = 0.0, s1 = 0.0;
#pragma unroll
      for (int j = 0; j < 16; j++){
        s0 += wr[j] * (double)hs[j];
        s1 += wr[16 + j] * (double)hs[16 + j];
      }
      hg[tid] = bias + s0 + s1;
    }
    __syncthreads();
    if (tid < 32){
      float xr  = xb[t * 96 + tid];
      float xz  = xb[t * 96 + 32 + tid];
      float xnv = xb[t * 96 + 64 + tid];
      float r = 1.f / (1.f + expf(-(float)((double)xr + hg[tid])));
      float z = 1.f / (1.f + expf(-(float)((double)xz + hg[32 + tid])));
      float n = tanhf((float)((double)xnv + (double)r * hg[64 + tid]));
      float h = (1.f - z) * n + z * hs[tid];
      hs[tid] = h;
      ob[t * 32 + tid] = h;
    }
    __syncthreads();
  }
}

// ---------------------------------------------------------------- tail
// conv1 relu conv2 tanh -> att; sd = att*(qw.outs); pyramid bins + score (f64)
__global__ __launch_bounds__(64) void attn_final_kernel(
    const float* __restrict__ outs, const float* __restrict__ w1,
    const float* __restrict__ b1, const float* __restrict__ w2,
    const float* __restrict__ b2, const float* __restrict__ qw,
    const float* __restrict__ qb, const float* __restrict__ rw,
    const float* __restrict__ rb, float* __restrict__ out){
  const int b = blockIdx.x, lane = threadIdx.x;
  __shared__ float a1[286];
  __shared__ double attv[272];
  __shared__ double sd[272];
  __shared__ float w1s[480];
  __shared__ float qws[32];
  const float* ob = outs + (size_t)b * 300 * 32;
  for (int i = lane; i < 480; i += 64) w1s[i] = w1[i];
  if (lane < 32) qws[lane] = qw[lane];
  __syncthreads();
  const double bb1 = (double)b1[0];
  for (int t = lane; t < 286; t += 64){
    double s = bb1;
    for (int k = 0; k < 15; k++){
      const float* row = ob + (t + k) * 32;
#pragma unroll
      for (int c = 0; c < 32; c++) s += (double)row[c] * (double)w1s[c * 15 + k];
    }
    a1[t] = fmaxf((float)s, 0.f);
  }
  __syncthreads();
  const double bb2 = (double)b2[0];
  for (int t = lane; t < 272; t += 64){
    double s = bb2;
#pragma unroll
    for (int k = 0; k < 15; k++) s += (double)a1[t + k] * (double)w2[k];
    double a = tanh(s);
    attv[t] = a;
    const float* row = ob + (t + 14) * 32;
    double d = 0.0;
#pragma unroll
    for (int c = 0; c < 32; c++) d += (double)row[c] * (double)qws[c];
    sd[t] = a * d;
  }
  __syncthreads();
  const double qb0 = (double)qb[0];
  double part = 0.0;
  double msum = 0.0;
  for (int t = lane; t < 272; t += 64) msum += sd[t];
  part += (double)rw[0] * (msum / 272.0);
  if (lane == 0) part += (double)rw[0] * qb0 + (double)rb[0];
  for (int j = lane; j < 126; j += 64){
    int mcur = 2, i = j;
    while (i >= mcur){ i -= mcur; mcur <<= 1; }   // decode (scale, bin idx)
    int s = (i * 272) / mcur;
    int e = ((i + 1) * 272 + mcur - 1) / mcur;
    double S = 0.0, A = 0.0;
    for (int n = s; n < e; n++){ S += sd[n]; A += attv[n]; }
    part += (double)rw[1 + j] * (S / A + qb0);
  }
#pragma unroll
  for (int o = 32; o > 0; o >>= 1) part += __shfl_xor(part, o);
  if (lane == 0) out[b] = (float)part;
}

// ---------------------------------------------------------------- launch
extern "C" void kernel_launch(void* const* d_in, const int* in_sizes, int n_in,
                              void* d_out, int out_size, void* d_ws, size_t ws_size,
                              hipStream_t stream){
  const float* input     = (const float*)d_in[0];
  const float* mean_var  = (const float*)d_in[2];
  const float* std_var   = (const float*)d_in[3];
  const float* mean_mean = (const float*)d_in[4];
  const float* std_mean  = (const float*)d_in[5];
  const float* ca1w = (const float*)d_in[6];
  const float* ca1b = (const float*)d_in[7];
  const float* ca2w = (const float*)d_in[8];
  const float* ca2b = (const float*)d_in[9];
  const float* annw = (const float*)d_in[10];
  const float* annb = (const float*)d_in[11];
  const float* wih  = (const float*)d_in[12];
  const float* whh  = (const float*)d_in[13];
  const float* bih  = (const float*)d_in[14];
  const float* bhh  = (const float*)d_in[15];
  const float* qw   = (const float*)d_in[16];
  const float* qb   = (const float*)d_in[17];
  const float* aw1  = (const float*)d_in[18];
  const float* ab1  = (const float*)d_in[19];
  const float* aw2  = (const float*)d_in[20];
  const float* ab2  = (const float*)d_in[21];
  const float* rw   = (const float*)d_in[22];
  const float* rb   = (const float*)d_in[23];
  float* out = (float*)d_out;

  char* ws = (char*)d_ws;
  size_t off = 0;
  auto alloc = [&](size_t bytes){
    size_t o = off; off += (bytes + 255) & ~(size_t)255; return o;
  };
  float* h1    = (float*)(ws + alloc((size_t)19200 * 320 * 4));   //  24.6 MB
  float* feat  = (float*)(ws + alloc((size_t)19200 * 1472 * 4));  // 113.0 MB
  float* xg    = (float*)(ws + alloc((size_t)19200 * 96 * 4));    //   7.4 MB
  float* outsb = (float*)(ws + alloc((size_t)19200 * 32 * 4));    //   2.5 MB
  float* w1p   = (float*)(ws + alloc((size_t)320 * 2944 * 4));    //   3.8 MB
  float* wc    = (float*)(ws + alloc((size_t)96 * 1472 * 4));     //   0.6 MB
  double* mu   = (double*)(ws + alloc(2944 * 8));
  double* rinv = (double*)(ws + alloc(2944 * 8));
  float* b1p   = (float*)(ws + alloc(320 * 4));
  float* bc    = (float*)(ws + alloc(96 * 4));
  (void)ws_size; (void)in_sizes; (void)n_in; (void)out_size;

  prep_params_kernel<<<12, 256, 0, stream>>>(mean_var, std_var, mean_mean, std_mean, mu, rinv);
  fold_w1_kernel<<<3680, 256, 0, stream>>>(ca1w, rinv, w1p);
  b1p_kernel<<<320, 64, 0, stream>>>(ca1w, ca1b, mu, rinv, b1p);
  make_wc_kernel<<<553, 256, 0, stream>>>(wih, annw, annb, bih, wc, bc);
  gemm1_kernel<<<240, 256, 0, stream>>>(input, w1p, b1p, h1);
  gemm2_kernel<<<dim3(23, 150), 256, 0, stream>>>(h1, ca2w, ca2b, input, mu, rinv, feat);
  gemm3_kernel<<<300, 256, 0, stream>>>(feat, wc, bc, xg);
  gru_kernel<<<64, 128, 0, stream>>>(xg, whh, bhh, outsb);
  attn_final_kernel<<<64, 64, 0, stream>>>(outsb, aw1, ab1, aw2, ab2, qw, qb, rw, rb, out);
}